// Round 4
// baseline (202.477 us; speedup 1.0000x reference)
//
#include <hip/hip_runtime.h>
#include <math.h>

namespace {
typedef float v2f __attribute__((ext_vector_type(2)));

constexpr int B   = 16;
constexpr int CH  = 4;
constexpr int H   = 512;
constexpr int W   = 512;
constexpr int HID = 8;
constexpr int PX  = 4;   // pixels per thread; one wave covers 256 contiguous cols

static __device__ __forceinline__ v2f splat(float f) { v2f r; r.x = f; r.y = f; return r; }

// Thread -> 4 consecutive pixels (all 4 channels). 8 waves/SIMD target (VGPR<=64).
__global__ __launch_bounds__(256, 8) void ca_kernel(
    const float* __restrict__ x,      // [16,4,512,512]
    const float* __restrict__ w1w,    // [8,16]
    const float* __restrict__ w1b,    // [8]
    const float* __restrict__ w2w,    // [4,8]
    const float* __restrict__ noise,  // [16,1,512,512]
    float* __restrict__ out)          // [16,4,512,512]
{
    const int idx  = blockIdx.x * 256 + threadIdx.x;
    const int lane = threadIdx.x & 63;
    const int w4 = idx & (W / PX - 1);       // 0..127
    const int h  = (idx >> 7) & (H - 1);     // 0..511
    const int b  = idx >> 16;                // 0..15

    const int w0 = w4 << 2;
    const int hm = (h - 1) & (H - 1);
    const int hp = (h + 1) & (H - 1);
    const int S  = (w4 & 64) << 2;           // wave segment start col: 0 or 256
    const bool edge = (lane == 0) || (lane == 63);
    // halo column this edge lane fetches: left-of-segment (lane0) / right-of-segment (lane63)
    const int hcol = (S + (lane == 0 ? W - 1 : 256)) & (W - 1);
    const int lm1 = (lane + 63) & 63;
    const int lp1 = (lane + 1) & 63;

    // hidden pre-activations: v2f per (hidden unit, pixel-pair)
    v2f hpre[HID][2];
#pragma unroll
    for (int o = 0; o < HID; ++o) {
        const v2f bo = splat(w1b[o]);        // uniform scalar load
        hpre[o][0] = bo; hpre[o][1] = bo;
    }

#pragma unroll
    for (int c = 0; c < CH; ++c) {
        const float* base = x + (size_t)(b * CH + c) * (H * W);
        const float* rt = base + hm * W;
        const float* rc = base + h  * W;
        const float* rb = base + hp * W;

        const float4 t4 = *(const float4*)(rt + w0);
        const float4 c4 = *(const float4*)(rc + w0);
        const float4 b4 = *(const float4*)(rb + w0);

        // segment-boundary halo: exec-masked loads on lanes {0,63} only
        float th = 0.f, mh = 0.f, bh = 0.f;
        if (edge) { th = rt[hcol]; mh = rc[hcol]; bh = rb[hcol]; }
        const float sh = fmaf(2.f, mh, th + bh);
        const float dh = bh - th;

        const float tt[4] = { t4.x, t4.y, t4.z, t4.w };
        const float mm[4] = { c4.x, c4.y, c4.z, c4.w };
        const float bb[4] = { b4.x, b4.y, b4.z, b4.w };

        // vertical column sums: [1,2,1] and [-1,0,1]
        float s[4], d[4];
#pragma unroll
        for (int k = 0; k < 4; ++k) {
            s[k] = fmaf(2.f, mm[k], tt[k] + bb[k]);
            d[k] = bb[k] - tt[k];
        }

        // neighbor halos: wave shuffle, overridden at segment edges by loaded halo
        float sl = __shfl(s[3], lm1, 64); if (lane == 0)  sl = sh;
        float sr = __shfl(s[0], lp1, 64); if (lane == 63) sr = sh;
        float dl = __shfl(d[3], lm1, 64); if (lane == 0)  dl = dh;
        float dr = __shfl(d[0], lp1, 64); if (lane == 63) dr = dh;

        const float se[6] = { sl, s[0], s[1], s[2], s[3], sr };
        const float de[6] = { dl, d[0], d[1], d[2], d[3], dr };

#pragma unroll
        for (int p = 0; p < 2; ++p) {
            const int j0 = 2 * p, j1 = 2 * p + 1;
            v2f id, sx, sy, lp;
            id.x = mm[j0]; id.y = mm[j1];
            sx.x = se[j0 + 2] - se[j0];            sx.y = se[j1 + 2] - se[j1];
            sy.x = fmaf(2.f, de[j0 + 1], de[j0] + de[j0 + 2]);
            sy.y = fmaf(2.f, de[j1 + 1], de[j1] + de[j1 + 2]);
            lp.x = fmaf(-16.f, mm[j0], fmaf(2.f, se[j0 + 1], se[j0] + se[j0 + 2]));
            lp.y = fmaf(-16.f, mm[j1], fmaf(2.f, se[j1 + 1], se[j1] + se[j1 + 2]));

            // packed fp32 FMAs; w1 offsets compile-time constant -> scalar (K$) loads
#pragma unroll
            for (int o = 0; o < HID; ++o) {
                const float* w1r = w1w + o * 16 + c * 4;
                v2f acc = hpre[o][p];
                acc = __builtin_elementwise_fma(id, splat(w1r[0]), acc);
                acc = __builtin_elementwise_fma(sx, splat(w1r[1]), acc);
                acc = __builtin_elementwise_fma(sy, splat(w1r[2]), acc);
                acc = __builtin_elementwise_fma(lp, splat(w1r[3]), acc);
                hpre[o][p] = acc;
            }
        }
    }

    // relu
#pragma unroll
    for (int o = 0; o < HID; ++o) {
        hpre[o][0] = __builtin_elementwise_max(hpre[o][0], splat(0.f));
        hpre[o][1] = __builtin_elementwise_max(hpre[o][1], splat(0.f));
    }

    // stochastic update mask: floor(U + 0.5), exact np semantics
    const float4 nz = *(const float4*)(noise + ((size_t)b * H + h) * W + w0);
    v2f m0, m1;
    m0.x = floorf(nz.x + 0.5f); m0.y = floorf(nz.y + 0.5f);
    m1.x = floorf(nz.z + 0.5f); m1.y = floorf(nz.w + 0.5f);

    // layer 2 + residual (center reloaded; asm barrier defeats CSE so regs stay freed)
#pragma unroll
    for (int c = 0; c < CH; ++c) {
        v2f d0 = splat(0.f), d1 = splat(0.f);
#pragma unroll
        for (int o = 0; o < HID; ++o) {
            const v2f wv = splat(w2w[c * HID + o]);   // uniform scalar load
            d0 = __builtin_elementwise_fma(hpre[o][0], wv, d0);
            d1 = __builtin_elementwise_fma(hpre[o][1], wv, d1);
        }
        const float* rc2 = x + ((size_t)(b * CH + c) * H + h) * W + w0;
        asm volatile("" : "+v"(rc2));    // opaque pointer: force fresh (L2-hot) reload
        const float4 cc = *(const float4*)rc2;
        float4 ov;
        ov.x = fmaf(d0.x, m0.x, cc.x);
        ov.y = fmaf(d0.y, m0.y, cc.y);
        ov.z = fmaf(d1.x, m1.x, cc.z);
        ov.w = fmaf(d1.y, m1.y, cc.w);
        *(float4*)(out + ((size_t)(b * CH + c) * H + h) * W + w0) = ov;
    }
}
} // namespace

extern "C" void kernel_launch(void* const* d_in, const int* in_sizes, int n_in,
                              void* d_out, int out_size, void* d_ws, size_t ws_size,
                              hipStream_t stream) {
    const float* x     = (const float*)d_in[0];
    const float* w1w   = (const float*)d_in[1];
    const float* w1b   = (const float*)d_in[2];
    const float* w2w   = (const float*)d_in[3];
    const float* noise = (const float*)d_in[4];
    float* out = (float*)d_out;

    const int total_threads = B * H * (W / PX);   // 1,048,576
    ca_kernel<<<total_threads / 256, 256, 0, stream>>>(x, w1w, w1b, w2w, noise, out);
}

// Round 5
// 95.162 us; speedup vs baseline: 2.1277x; 2.1277x over previous
//
#include <hip/hip_runtime.h>
#include <math.h>

namespace {
typedef float v2f __attribute__((ext_vector_type(2)));

constexpr int B   = 16;
constexpr int CH  = 4;
constexpr int H   = 512;
constexpr int W   = 512;
constexpr int HID = 8;
constexpr int PX  = 8;   // pixels per thread; one 64-lane wave = one full row

static __device__ __forceinline__ v2f splat(float f) { v2f r; r.x = f; r.y = f; return r; }

struct Rows { float4 t0, t1, c0, c1, b0, b1; };   // 3 rows x 8 cols = 24 VGPRs

// One thread computes 8 consecutive pixels (all 4 channels); channels are
// explicitly software-pipelined 2-deep to keep global loads in flight.
__global__ __launch_bounds__(256, 4) void ca_kernel(
    const float* __restrict__ x,      // [16,4,512,512]
    const float* __restrict__ w1w,    // [8,16]
    const float* __restrict__ w1b,    // [8]
    const float* __restrict__ w2w,    // [4,8]
    const float* __restrict__ noise,  // [16,1,512,512]
    float* __restrict__ out)          // [16,4,512,512]
{
    const int idx  = blockIdx.x * 256 + threadIdx.x;
    const int lane = threadIdx.x & 63;
    const int wg = idx & (W / PX - 1);       // 0..63 == lane (wave covers the row)
    const int h  = (idx >> 6) & (H - 1);     // 0..511
    const int b  = idx >> 15;                // 0..15

    const int w0 = wg << 3;
    const int hm = (h - 1) & (H - 1);        // wrapped row above
    const int hp = (h + 1) & (H - 1);        // wrapped row below
    const int lm1 = (lane + 63) & 63;        // W-wrap lives inside the wave
    const int lp1 = (lane + 1) & 63;

    const float* bx = x + (size_t)b * CH * H * W;

    auto LOAD = [&](int c) -> Rows {
        const float* base = bx + (size_t)c * (H * W);
        const float* rt = base + hm * W + w0;
        const float* rc = base + h  * W + w0;
        const float* rb = base + hp * W + w0;
        Rows r;
        r.t0 = *(const float4*)(rt);  r.t1 = *(const float4*)(rt + 4);
        r.c0 = *(const float4*)(rc);  r.c1 = *(const float4*)(rc + 4);
        r.b0 = *(const float4*)(rb);  r.b1 = *(const float4*)(rb + 4);
        return r;
    };

    // hidden pre-activations: v2f per (hidden unit, pixel-pair)
    v2f hpre[HID][4];
#pragma unroll
    for (int o = 0; o < HID; ++o) {
        const v2f bo = splat(w1b[o]);        // uniform scalar load
#pragma unroll
        for (int p = 0; p < 4; ++p) hpre[o][p] = bo;
    }

    Rows buf[2];                             // indices compile-time after unroll
    buf[0] = LOAD(0);

#pragma unroll
    for (int c = 0; c < CH; ++c) {
        // prefetch next channel into the idle buffer BEFORE consuming this one
        if (c + 1 < CH) buf[(c + 1) & 1] = LOAD(c + 1);
        const Rows R = buf[c & 1];

        const float tt[8] = { R.t0.x, R.t0.y, R.t0.z, R.t0.w, R.t1.x, R.t1.y, R.t1.z, R.t1.w };
        const float mm[8] = { R.c0.x, R.c0.y, R.c0.z, R.c0.w, R.c1.x, R.c1.y, R.c1.z, R.c1.w };
        const float bb[8] = { R.b0.x, R.b0.y, R.b0.z, R.b0.w, R.b1.x, R.b1.y, R.b1.z, R.b1.w };

        // vertical column sums: [1,2,1] and [-1,0,1]
        float s[8], d[8];
#pragma unroll
        for (int k = 0; k < 8; ++k) {
            s[k] = fmaf(2.f, mm[k], tt[k] + bb[k]);
            d[k] = bb[k] - tt[k];
        }

        // halo columns via wave-circular shuffle (no gather loads)
        const float sl = __shfl(s[7], lm1, 64);
        const float sr = __shfl(s[0], lp1, 64);
        const float dl = __shfl(d[7], lm1, 64);
        const float dr = __shfl(d[0], lp1, 64);

        const float se[10] = { sl, s[0], s[1], s[2], s[3], s[4], s[5], s[6], s[7], sr };
        const float de[10] = { dl, d[0], d[1], d[2], d[3], d[4], d[5], d[6], d[7], dr };

#pragma unroll
        for (int p = 0; p < 4; ++p) {
            const int j0 = 2 * p, j1 = 2 * p + 1;
            v2f id, sx, sy, lp;
            id.x = mm[j0]; id.y = mm[j1];
            sx.x = se[j0 + 2] - se[j0];            sx.y = se[j1 + 2] - se[j1];
            sy.x = fmaf(2.f, de[j0 + 1], de[j0] + de[j0 + 2]);
            sy.y = fmaf(2.f, de[j1 + 1], de[j1] + de[j1 + 2]);
            lp.x = fmaf(-16.f, mm[j0], fmaf(2.f, se[j0 + 1], se[j0] + se[j0 + 2]));
            lp.y = fmaf(-16.f, mm[j1], fmaf(2.f, se[j1 + 1], se[j1] + se[j1 + 2]));

            // packed fp32 FMAs; w1 offsets compile-time constant -> scalar (K$) loads
#pragma unroll
            for (int o = 0; o < HID; ++o) {
                const float* w1r = w1w + o * 16 + c * 4;
                v2f acc = hpre[o][p];
                acc = __builtin_elementwise_fma(id, splat(w1r[0]), acc);
                acc = __builtin_elementwise_fma(sx, splat(w1r[1]), acc);
                acc = __builtin_elementwise_fma(sy, splat(w1r[2]), acc);
                acc = __builtin_elementwise_fma(lp, splat(w1r[3]), acc);
                hpre[o][p] = acc;
            }
        }
    }

    // relu
#pragma unroll
    for (int o = 0; o < HID; ++o)
#pragma unroll
        for (int p = 0; p < 4; ++p)
            hpre[o][p] = __builtin_elementwise_max(hpre[o][p], splat(0.f));

    // stochastic update mask: floor(U + 0.5), exact np semantics
    const float* nrow = noise + ((size_t)b * H + h) * W + w0;
    const float4 n0 = *(const float4*)(nrow);
    const float4 n1 = *(const float4*)(nrow + 4);
    v2f msk[4];
    msk[0].x = floorf(n0.x + 0.5f); msk[0].y = floorf(n0.y + 0.5f);
    msk[1].x = floorf(n0.z + 0.5f); msk[1].y = floorf(n0.w + 0.5f);
    msk[2].x = floorf(n1.x + 0.5f); msk[2].y = floorf(n1.y + 0.5f);
    msk[3].x = floorf(n1.z + 0.5f); msk[3].y = floorf(n1.w + 0.5f);

    // layer 2 + residual; center row reloaded (L1/L2-hot) via CSE-opaque pointer
    // so its registers were free during the main loop
#pragma unroll
    for (int c = 0; c < CH; ++c) {
        v2f dd[4] = { splat(0.f), splat(0.f), splat(0.f), splat(0.f) };
#pragma unroll
        for (int o = 0; o < HID; ++o) {
            const v2f wv = splat(w2w[c * HID + o]);   // uniform scalar load
#pragma unroll
            for (int p = 0; p < 4; ++p)
                dd[p] = __builtin_elementwise_fma(hpre[o][p], wv, dd[p]);
        }
        const float* rc2 = bx + ((size_t)c * H + h) * W + w0;
        asm volatile("" : "+v"(rc2));        // opaque: force fresh reload, frees regs
        const float4 cc0 = *(const float4*)(rc2);
        const float4 cc1 = *(const float4*)(rc2 + 4);

        float* orow = out + ((size_t)(b * CH + c) * H + h) * W + w0;
        float4 o0, o1;
        o0.x = fmaf(dd[0].x, msk[0].x, cc0.x);
        o0.y = fmaf(dd[0].y, msk[0].y, cc0.y);
        o0.z = fmaf(dd[1].x, msk[1].x, cc0.z);
        o0.w = fmaf(dd[1].y, msk[1].y, cc0.w);
        o1.x = fmaf(dd[2].x, msk[2].x, cc1.x);
        o1.y = fmaf(dd[2].y, msk[2].y, cc1.y);
        o1.z = fmaf(dd[3].x, msk[3].x, cc1.z);
        o1.w = fmaf(dd[3].y, msk[3].y, cc1.w);
        *(float4*)(orow)     = o0;
        *(float4*)(orow + 4) = o1;
    }
}
} // namespace

extern "C" void kernel_launch(void* const* d_in, const int* in_sizes, int n_in,
                              void* d_out, int out_size, void* d_ws, size_t ws_size,
                              hipStream_t stream) {
    const float* x     = (const float*)d_in[0];
    const float* w1w   = (const float*)d_in[1];
    const float* w1b   = (const float*)d_in[2];
    const float* w2w   = (const float*)d_in[3];
    const float* noise = (const float*)d_in[4];
    float* out = (float*)d_out;

    const int total_threads = B * H * (W / PX);   // 524,288
    ca_kernel<<<total_threads / 256, 256, 0, stream>>>(x, w1w, w1b, w2w, noise, out);
}

// Round 6
// 39.864 us; speedup vs baseline: 5.0792x; 2.3872x over previous
//
#include <hip/hip_runtime.h>
#include <math.h>

namespace {
typedef float v2f __attribute__((ext_vector_type(2)));

constexpr int B   = 16;
constexpr int CH  = 4;
constexpr int H   = 512;
constexpr int W   = 512;
constexpr int HID = 8;
constexpr int PX  = 8;   // pixels per thread; one 64-lane wave = one full row

static __device__ __forceinline__ v2f splat(float f) { v2f r; r.x = f; r.y = f; return r; }

struct Rows { float4 t0, t1, c0, c1, b0, b1; };   // 3 rows x 8 cols = 24 VGPRs

// One thread computes 8 consecutive pixels (all 4 channels); channels are
// explicitly software-pipelined 2-deep to keep global loads in flight.
// NOTE: no occupancy arg in launch_bounds — forced caps (r4: cap=256/arg) spill.
__global__ __launch_bounds__(256) void ca_kernel(
    const float* __restrict__ x,      // [16,4,512,512]
    const float* __restrict__ w1w,    // [8,16]
    const float* __restrict__ w1b,    // [8]
    const float* __restrict__ w2w,    // [4,8]
    const float* __restrict__ noise,  // [16,1,512,512]
    float* __restrict__ out)          // [16,4,512,512]
{
    const int idx  = blockIdx.x * 256 + threadIdx.x;
    const int lane = threadIdx.x & 63;
    const int wg = idx & (W / PX - 1);       // 0..63 == lane (wave covers the row)
    const int h  = (idx >> 6) & (H - 1);     // 0..511
    const int b  = idx >> 15;                // 0..15

    const int w0 = wg << 3;
    const int hm = (h - 1) & (H - 1);        // wrapped row above
    const int hp = (h + 1) & (H - 1);        // wrapped row below
    const int lm1 = (lane + 63) & 63;        // W-wrap lives inside the wave
    const int lp1 = (lane + 1) & 63;

    const float* bx = x + (size_t)b * CH * H * W;

    auto LOAD = [&](int c) -> Rows {
        const float* base = bx + (size_t)c * (H * W);
        const float* rt = base + hm * W + w0;
        const float* rc = base + h  * W + w0;
        const float* rb = base + hp * W + w0;
        Rows r;
        r.t0 = *(const float4*)(rt);  r.t1 = *(const float4*)(rt + 4);
        r.c0 = *(const float4*)(rc);  r.c1 = *(const float4*)(rc + 4);
        r.b0 = *(const float4*)(rb);  r.b1 = *(const float4*)(rb + 4);
        return r;
    };

    // issue noise load early too — independent of everything until epilogue
    const float* nrow = noise + ((size_t)b * H + h) * W + w0;
    const float4 n0 = *(const float4*)(nrow);
    const float4 n1 = *(const float4*)(nrow + 4);

    // hidden pre-activations: v2f per (hidden unit, pixel-pair)
    v2f hpre[HID][4];
#pragma unroll
    for (int o = 0; o < HID; ++o) {
        const v2f bo = splat(w1b[o]);        // uniform scalar load
#pragma unroll
        for (int p = 0; p < 4; ++p) hpre[o][p] = bo;
    }

    Rows buf[2];                             // indices compile-time after unroll
    buf[0] = LOAD(0);

#pragma unroll
    for (int c = 0; c < CH; ++c) {
        // prefetch next channel into the idle buffer BEFORE consuming this one
        if (c + 1 < CH) buf[(c + 1) & 1] = LOAD(c + 1);
        const Rows R = buf[c & 1];

        const float tt[8] = { R.t0.x, R.t0.y, R.t0.z, R.t0.w, R.t1.x, R.t1.y, R.t1.z, R.t1.w };
        const float mm[8] = { R.c0.x, R.c0.y, R.c0.z, R.c0.w, R.c1.x, R.c1.y, R.c1.z, R.c1.w };
        const float bb[8] = { R.b0.x, R.b0.y, R.b0.z, R.b0.w, R.b1.x, R.b1.y, R.b1.z, R.b1.w };

        // vertical column sums: [1,2,1] and [-1,0,1]
        float s[8], d[8];
#pragma unroll
        for (int k = 0; k < 8; ++k) {
            s[k] = fmaf(2.f, mm[k], tt[k] + bb[k]);
            d[k] = bb[k] - tt[k];
        }

        // halo columns via wave-circular shuffle (no gather loads)
        const float sl = __shfl(s[7], lm1, 64);
        const float sr = __shfl(s[0], lp1, 64);
        const float dl = __shfl(d[7], lm1, 64);
        const float dr = __shfl(d[0], lp1, 64);

        const float se[10] = { sl, s[0], s[1], s[2], s[3], s[4], s[5], s[6], s[7], sr };
        const float de[10] = { dl, d[0], d[1], d[2], d[3], d[4], d[5], d[6], d[7], dr };

#pragma unroll
        for (int p = 0; p < 4; ++p) {
            const int j0 = 2 * p, j1 = 2 * p + 1;
            v2f id, sx, sy, lp;
            id.x = mm[j0]; id.y = mm[j1];
            sx.x = se[j0 + 2] - se[j0];            sx.y = se[j1 + 2] - se[j1];
            sy.x = fmaf(2.f, de[j0 + 1], de[j0] + de[j0 + 2]);
            sy.y = fmaf(2.f, de[j1 + 1], de[j1] + de[j1 + 2]);
            lp.x = fmaf(-16.f, mm[j0], fmaf(2.f, se[j0 + 1], se[j0] + se[j0 + 2]));
            lp.y = fmaf(-16.f, mm[j1], fmaf(2.f, se[j1 + 1], se[j1] + se[j1 + 2]));

            // packed fp32 FMAs; w1 offsets compile-time constant -> scalar (K$) loads
#pragma unroll
            for (int o = 0; o < HID; ++o) {
                const float* w1r = w1w + o * 16 + c * 4;
                v2f acc = hpre[o][p];
                acc = __builtin_elementwise_fma(id, splat(w1r[0]), acc);
                acc = __builtin_elementwise_fma(sx, splat(w1r[1]), acc);
                acc = __builtin_elementwise_fma(sy, splat(w1r[2]), acc);
                acc = __builtin_elementwise_fma(lp, splat(w1r[3]), acc);
                hpre[o][p] = acc;
            }
        }
    }

    // relu
#pragma unroll
    for (int o = 0; o < HID; ++o)
#pragma unroll
        for (int p = 0; p < 4; ++p)
            hpre[o][p] = __builtin_elementwise_max(hpre[o][p], splat(0.f));

    // stochastic update mask: floor(U + 0.5), exact np semantics
    v2f msk[4];
    msk[0].x = floorf(n0.x + 0.5f); msk[0].y = floorf(n0.y + 0.5f);
    msk[1].x = floorf(n0.z + 0.5f); msk[1].y = floorf(n0.w + 0.5f);
    msk[2].x = floorf(n1.x + 0.5f); msk[2].y = floorf(n1.y + 0.5f);
    msk[3].x = floorf(n1.z + 0.5f); msk[3].y = floorf(n1.w + 0.5f);

    // layer 2 + residual; center row reloaded (L1/L2-hot) via CSE-opaque pointer
    // so its registers were free during the main loop
#pragma unroll
    for (int c = 0; c < CH; ++c) {
        v2f dd[4] = { splat(0.f), splat(0.f), splat(0.f), splat(0.f) };
#pragma unroll
        for (int o = 0; o < HID; ++o) {
            const v2f wv = splat(w2w[c * HID + o]);   // uniform scalar load
#pragma unroll
            for (int p = 0; p < 4; ++p)
                dd[p] = __builtin_elementwise_fma(hpre[o][p], wv, dd[p]);
        }
        const float* rc2 = bx + ((size_t)c * H + h) * W + w0;
        asm volatile("" : "+v"(rc2));        // opaque: force fresh reload, frees regs
        const float4 cc0 = *(const float4*)(rc2);
        const float4 cc1 = *(const float4*)(rc2 + 4);

        float* orow = out + ((size_t)(b * CH + c) * H + h) * W + w0;
        float4 o0, o1;
        o0.x = fmaf(dd[0].x, msk[0].x, cc0.x);
        o0.y = fmaf(dd[0].y, msk[0].y, cc0.y);
        o0.z = fmaf(dd[1].x, msk[1].x, cc0.z);
        o0.w = fmaf(dd[1].y, msk[1].y, cc0.w);
        o1.x = fmaf(dd[2].x, msk[2].x, cc1.x);
        o1.y = fmaf(dd[2].y, msk[2].y, cc1.y);
        o1.z = fmaf(dd[3].x, msk[3].x, cc1.z);
        o1.w = fmaf(dd[3].y, msk[3].y, cc1.w);
        *(float4*)(orow)     = o0;
        *(float4*)(orow + 4) = o1;
    }
}
} // namespace

extern "C" void kernel_launch(void* const* d_in, const int* in_sizes, int n_in,
                              void* d_out, int out_size, void* d_ws, size_t ws_size,
                              hipStream_t stream) {
    const float* x     = (const float*)d_in[0];
    const float* w1w   = (const float*)d_in[1];
    const float* w1b   = (const float*)d_in[2];
    const float* w2w   = (const float*)d_in[3];
    const float* noise = (const float*)d_in[4];
    float* out = (float*)d_out;

    const int total_threads = B * H * (W / PX);   // 524,288
    ca_kernel<<<total_threads / 256, 256, 0, stream>>>(x, w1w, w1b, w2w, noise, out);
}

// Round 7
// 35.748 us; speedup vs baseline: 5.6641x; 1.1151x over previous
//
#include <hip/hip_runtime.h>
#include <math.h>

namespace {
typedef float v2f __attribute__((ext_vector_type(2)));

constexpr int B = 16, CH = 4, H = 512, W = 512, HID = 8;
constexpr int STRIP  = 8;            // rows per block
constexpr int SLOT_F = CH * W;       // floats per ring slot (one row, all channels) = 8KB
constexpr int NSLOT  = 5;            // ring depth: compute r-1..r+1 while DMA r+3

static __device__ __forceinline__ v2f splat(float f){ v2f r; r.x=f; r.y=f; return r; }

// Block = 256 thr = 4 waves = one full image row (2 px/thread, all 4 channels).
// Rows of an 8-row strip march through a 5-slot LDS ring fed by global_load_lds.
__global__ __launch_bounds__(256) void ca_kernel(
    const float* __restrict__ x,      // [16,4,512,512]
    const float* __restrict__ w1w,    // [8,16]
    const float* __restrict__ w1b,    // [8]
    const float* __restrict__ w2w,    // [4,8]
    const float* __restrict__ noise,  // [16,1,512,512]
    float* __restrict__ out)          // [16,4,512,512]
{
    __shared__ float smem[NSLOT * SLOT_F];   // 40 KB -> 4 blocks/CU

    const int blk  = blockIdx.x;             // 1024 blocks
    const int b    = blk >> 6;               // image
    const int hs   = (blk & 63) * STRIP;     // strip start row
    const int tid  = threadIdx.x;
    const int wv   = tid >> 6;
    const int lane = tid & 63;
    const int w0   = tid << 1;               // 2 consecutive columns per thread
    const int colL = (w0 - 1) & (W - 1);
    const int colR = (w0 + 2) & (W - 1);

    const float* xb = x + (size_t)b * CH * H * W;

    // DMA one full row (4 ch) of row q (unwrapped) into ring slot `slot`.
    // 8KB row = 8 chunks of 1KB; wave wv issues chunks {wv, wv+4}:
    // chunk k -> ch = k>>1, half = k&1. LDS dest is wave-uniform; lane adds 16B.
    auto dma = [&](int q, int slot) {
        const int row  = q & (H - 1);
        const int half = wv & 1;
#pragma unroll
        for (int j = 0; j < 2; ++j) {
            const int ch = (wv >> 1) + 2 * j;
            const float* g = xb + ((size_t)ch * H + row) * W + half * 256 + lane * 4;
            const float* l = &smem[slot * SLOT_F + ch * W + half * 256];
            __builtin_amdgcn_global_load_lds(
                (const __attribute__((address_space(1))) void*)g,
                (__attribute__((address_space(3))) void*)l, 16, 0, 0);
        }
    };

    // prologue: rows hs-1, hs, hs+1 | fence | hs+2  (slots 0,1,2,3)
    dma(hs - 1, 0); dma(hs, 1); dma(hs + 1, 2);
    asm volatile("" ::: "memory");
    dma(hs + 2, 3);

    // ring slot registers: row q -> slot (q - hs + 1) % 5
    int sA = 0, sB = 1, sC = 2, sW = 4;      // r-1, r, r+1, write-slot for r+3

    for (int i = 0; i < STRIP; ++i) {
        const int r = hs + i;
        // counted waits (worst-case-safe vs compiler VMEM reordering within windows):
        // guarantee row r+1's DMA (issued 2 iterations ago) has landed; never drain
        // the in-flight prefetches.
        if (i == 0)              asm volatile("s_waitcnt vmcnt(2)" ::: "memory");
        else if (i == STRIP - 1) asm volatile("s_waitcnt vmcnt(5)" ::: "memory");
        else                     asm volatile("s_waitcnt vmcnt(7)" ::: "memory");
        __builtin_amdgcn_s_barrier();
        if (i + 3 <= STRIP) dma(r + 3, sW);  // prefetch 3 rows ahead

        // ---- compute row r from LDS slots sA (r-1), sB (r), sC (r+1) ----
        v2f hpre[HID];
#pragma unroll
        for (int o = 0; o < HID; ++o) hpre[o] = splat(w1b[o]);
        v2f xcv[CH];

#pragma unroll
        for (int ch = 0; ch < CH; ++ch) {
            const float* rT = &smem[sA * SLOT_F + ch * W];
            const float* rM = &smem[sB * SLOT_F + ch * W];
            const float* rB2 = &smem[sC * SLOT_F + ch * W];
            const float2 t2 = *(const float2*)&rT[w0];
            const float2 m2 = *(const float2*)&rM[w0];
            const float2 b2 = *(const float2*)&rB2[w0];
            const float tL = rT[colL], tR = rT[colR];
            const float mL = rM[colL], mR = rM[colR];
            const float bL = rB2[colL], bR = rB2[colR];

            v2f tv; tv.x = t2.x; tv.y = t2.y;
            v2f mv; mv.x = m2.x; mv.y = m2.y;
            v2f bv; bv.x = b2.x; bv.y = b2.y;
            const v2f sP = __builtin_elementwise_fma(splat(2.f), mv, tv + bv);
            const v2f dP = bv - tv;
            const float sL = fmaf(2.f, mL, tL + bL);
            const float sR = fmaf(2.f, mR, tR + bR);
            const float dL = bL - tL, dR = bR - tR;

            v2f sprev; sprev.x = sL;   sprev.y = sP.x;
            v2f snext; snext.x = sP.y; snext.y = sR;
            v2f dprev; dprev.x = dL;   dprev.y = dP.x;
            v2f dnext; dnext.x = dP.y; dnext.y = dR;

            const v2f id = mv;
            const v2f sx = snext - sprev;
            const v2f sy = __builtin_elementwise_fma(splat(2.f), dP, dprev + dnext);
            const v2f lp = __builtin_elementwise_fma(splat(-16.f), mv,
                            __builtin_elementwise_fma(splat(2.f), sP, sprev + snext));
            xcv[ch] = mv;                     // residual from LDS (no global reload)
#pragma unroll
            for (int o = 0; o < HID; ++o) {
                const float* w1r = w1w + o * 16 + ch * 4;   // scalar (K$) loads
                v2f a = hpre[o];
                a = __builtin_elementwise_fma(id, splat(w1r[0]), a);
                a = __builtin_elementwise_fma(sx, splat(w1r[1]), a);
                a = __builtin_elementwise_fma(sy, splat(w1r[2]), a);
                a = __builtin_elementwise_fma(lp, splat(w1r[3]), a);
                hpre[o] = a;
            }
        }

#pragma unroll
        for (int o = 0; o < HID; ++o)
            hpre[o] = __builtin_elementwise_max(hpre[o], splat(0.f));

        const float2 nz = *(const float2*)&noise[((size_t)b * H + r) * W + w0];
        v2f mk; mk.x = floorf(nz.x + 0.5f); mk.y = floorf(nz.y + 0.5f);

#pragma unroll
        for (int ch = 0; ch < CH; ++ch) {
            v2f dd = splat(0.f);
#pragma unroll
            for (int o = 0; o < HID; ++o)
                dd = __builtin_elementwise_fma(hpre[o], splat(w2w[ch * HID + o]), dd);
            const v2f ov = __builtin_elementwise_fma(dd, mk, xcv[ch]);
            float2 st; st.x = ov.x; st.y = ov.y;
            *(float2*)&out[((size_t)(b * CH + ch) * H + r) * W + w0] = st;
        }

        // advance ring
        sA = sB; sB = sC;
        sC = (sC + 1 == NSLOT) ? 0 : sC + 1;
        sW = (sW + 1 == NSLOT) ? 0 : sW + 1;
    }
}
} // namespace

extern "C" void kernel_launch(void* const* d_in, const int* in_sizes, int n_in,
                              void* d_out, int out_size, void* d_ws, size_t ws_size,
                              hipStream_t stream) {
    const float* x     = (const float*)d_in[0];
    const float* w1w   = (const float*)d_in[1];
    const float* w1b   = (const float*)d_in[2];
    const float* w2w   = (const float*)d_in[3];
    const float* noise = (const float*)d_in[4];
    float* out = (float*)d_out;

    const int blocks = B * (H / STRIP);   // 1024 = exactly 4 blocks/CU
    ca_kernel<<<blocks, 256, 0, stream>>>(x, w1w, w1b, w2w, noise, out);
}

// Round 8
// 34.850 us; speedup vs baseline: 5.8099x; 1.0257x over previous
//
#include <hip/hip_runtime.h>
#include <math.h>

namespace {
typedef float v2f __attribute__((ext_vector_type(2)));

constexpr int B = 16, CH = 4, H = 512, W = 512, HID = 8;
constexpr int STRIP  = 16;           // rows per block
constexpr int SLOT_F = CH * W;       // one full row, all channels = 8 KB
constexpr int NSLOT  = 8;            // 64 KB ring -> 2 blocks/CU, grid 512 all-resident

static __device__ __forceinline__ v2f splat(float f){ v2f r; r.x=f; r.y=f; return r; }

// Block = 512 thr = 8 waves; per pair-iter waves 0-3 compute row r, 4-7 row r+1.
// Rows march through an 8-slot LDS ring fed by global_load_lds, prefetched
// 2 pair-iters (~4 rows) ahead with counted vmcnt (never drained mid-loop).
__global__ __launch_bounds__(512) void ca_kernel(
    const float* __restrict__ x,      // [16,4,512,512]
    const float* __restrict__ w1w,    // [8,16]
    const float* __restrict__ w1b,    // [8]
    const float* __restrict__ w2w,    // [4,8]
    const float* __restrict__ noise,  // [16,1,512,512]
    float* __restrict__ out)          // [16,4,512,512]
{
    __shared__ float smem[NSLOT * SLOT_F];

    const int blk  = blockIdx.x;             // 512 blocks
    const int b    = blk >> 5;               // image
    const int hs   = (blk & 31) * STRIP;     // strip start row
    const int tid  = threadIdx.x;
    const int wv   = tid >> 6;               // wave 0..7
    const int lane = tid & 63;
    const int rsel = tid >> 8;               // 0: row r, 1: row r+1
    const int w0   = (tid & 255) << 1;       // 2 consecutive columns
    const int pl   = (w0 - 2) & (W - 1);     // left neighbor pair (wraps in-slot)
    const int pr   = (w0 + 2) & (W - 1);     // right neighbor pair

    const float* xb = x + (size_t)b * CH * H * W;
    const int dch   = wv >> 1;               // DMA: wave -> (channel, half-row)
    const int dhalf = wv & 1;

    // stage one full row (4ch, 8KB): each wave one 1KB global_load_lds chunk
    auto dma = [&](int q) {
        const int row  = q & (H - 1);
        const int slot = (q - hs + 1) & (NSLOT - 1);
        const float* g = xb + ((size_t)dch * H + row) * W + dhalf * 256 + lane * 4;
        const float* l = &smem[slot * SLOT_F + dch * W + dhalf * 256]; // wave-uniform base
        __builtin_amdgcn_global_load_lds(
            (const __attribute__((address_space(1))) void*)g,
            (__attribute__((address_space(3))) void*)l, 16, 0, 0);
    };

    // prologue: rows hs-1 .. hs+4 (6 loads/wave)
    dma(hs - 1); dma(hs); dma(hs + 1); dma(hs + 2); dma(hs + 3); dma(hs + 4);

    auto step = [&](int k) {
        __builtin_amdgcn_s_barrier();
        if (k <= 5) { dma(hs + 2 * k + 5); dma(hs + 2 * k + 6); }  // 2 iters ahead

        const int r  = hs + 2 * k + rsel;
        const int sT = (2 * k + rsel)     & 7;   // slot of row r-1
        const int sM = (2 * k + rsel + 1) & 7;   // row r
        const int sB = (2 * k + rsel + 2) & 7;   // row r+1

        v2f hpre[HID];
#pragma unroll
        for (int o = 0; o < HID; ++o) hpre[o] = splat(w1b[o]);
        v2f xcv[CH];

#pragma unroll
        for (int ch = 0; ch < CH; ++ch) {
            const float* T  = &smem[sT * SLOT_F + ch * W];
            const float* M  = &smem[sM * SLOT_F + ch * W];
            const float* Bt = &smem[sB * SLOT_F + ch * W];
            // all reads are ds_read_b64 at byte 8*lane (+const) -> 2-way, conflict-free
            const float2 t2 = *(const float2*)&T[w0];
            const float2 tl = *(const float2*)&T[pl];
            const float2 tr = *(const float2*)&T[pr];
            const float2 m2 = *(const float2*)&M[w0];
            const float2 ml = *(const float2*)&M[pl];
            const float2 mr = *(const float2*)&M[pr];
            const float2 b2 = *(const float2*)&Bt[w0];
            const float2 bl = *(const float2*)&Bt[pl];
            const float2 br = *(const float2*)&Bt[pr];

            v2f tv; tv.x = t2.x; tv.y = t2.y;
            v2f mv; mv.x = m2.x; mv.y = m2.y;
            v2f bv; bv.x = b2.x; bv.y = b2.y;
            const v2f sP = __builtin_elementwise_fma(splat(2.f), mv, tv + bv);
            const v2f dP = bv - tv;
            const float sL = fmaf(2.f, ml.y, tl.y + bl.y);   // col w0-1
            const float dL = bl.y - tl.y;
            const float sR = fmaf(2.f, mr.x, tr.x + br.x);   // col w0+2
            const float dR = br.x - tr.x;

            v2f sprev; sprev.x = sL;   sprev.y = sP.x;
            v2f snext; snext.x = sP.y; snext.y = sR;
            v2f dprev; dprev.x = dL;   dprev.y = dP.x;
            v2f dnext; dnext.x = dP.y; dnext.y = dR;

            const v2f id = mv;
            const v2f sx = snext - sprev;
            const v2f sy = __builtin_elementwise_fma(splat(2.f), dP, dprev + dnext);
            const v2f lp = __builtin_elementwise_fma(splat(-16.f), mv,
                             __builtin_elementwise_fma(splat(2.f), sP, sprev + snext));
            xcv[ch] = mv;                      // residual straight from LDS
#pragma unroll
            for (int o = 0; o < HID; ++o) {
                const float* w1r = w1w + o * 16 + ch * 4;   // scalar (K$) loads
                v2f a = hpre[o];
                a = __builtin_elementwise_fma(id, splat(w1r[0]), a);
                a = __builtin_elementwise_fma(sx, splat(w1r[1]), a);
                a = __builtin_elementwise_fma(sy, splat(w1r[2]), a);
                a = __builtin_elementwise_fma(lp, splat(w1r[3]), a);
                hpre[o] = a;
            }
        }

#pragma unroll
        for (int o = 0; o < HID; ++o)
            hpre[o] = __builtin_elementwise_max(hpre[o], splat(0.f));

        const float2 nz = *(const float2*)&noise[((size_t)b * H + r) * W + w0];
        v2f mk; mk.x = floorf(nz.x + 0.5f); mk.y = floorf(nz.y + 0.5f);

#pragma unroll
        for (int ch = 0; ch < CH; ++ch) {
            v2f dd = splat(0.f);
#pragma unroll
            for (int o = 0; o < HID; ++o)
                dd = __builtin_elementwise_fma(hpre[o], splat(w2w[ch * HID + o]), dd);
            const v2f ov = __builtin_elementwise_fma(dd, mk, xcv[ch]);
            float2 st; st.x = ov.x; st.y = ov.y;
            *(float2*)&out[((size_t)(b * CH + ch) * H + r) * W + w0] = st;
        }
    };

    // counted waits, derived counting LOAD-class ops only (dma+noise) so the
    // schedule is conservative under either vmcnt-store-counting semantics.
#define WAITVM(n) asm volatile("s_waitcnt vmcnt(" #n ")" ::: "memory")
    WAITVM(2); step(0);
    WAITVM(3); step(1);
    WAITVM(4); step(2);
    WAITVM(4); step(3);
    WAITVM(4); step(4);
    WAITVM(4); step(5);
    WAITVM(4); step(6);
    WAITVM(2); step(7);
#undef WAITVM
}
} // namespace

extern "C" void kernel_launch(void* const* d_in, const int* in_sizes, int n_in,
                              void* d_out, int out_size, void* d_ws, size_t ws_size,
                              hipStream_t stream) {
    const float* x     = (const float*)d_in[0];
    const float* w1w   = (const float*)d_in[1];
    const float* w1b   = (const float*)d_in[2];
    const float* w2w   = (const float*)d_in[3];
    const float* noise = (const float*)d_in[4];
    float* out = (float*)d_out;

    const int blocks = B * (H / STRIP);   // 512 = exactly 2 blocks/CU, all resident
    ca_kernel<<<blocks, 512, 0, stream>>>(x, w1w, w1b, w2w, noise, out);
}